// Round 4
// baseline (243.410 us; speedup 1.0000x reference)
//
#include <hip/hip_runtime.h>
#include <math.h>

#define Mq 12288          // B*T
#define Nq 768            // C (per-matrix output width)
#define Kq 768            // C (reduce dim)
#define Tq 768
#define Bq 16
#define Cq 768
#define BK 64             // K-tile depth (bf16) = 128 B = 8 x 16B chunks
#define BM 128            // token tile
#define BN 256            // channel tile
#define KT (Kq / BK)      // 12 K-tiles
#define BUFE 24576        // LDS elems per buffer: W 256x64 (16384) + X 128x64 (8192)

typedef __bf16 bf16x8 __attribute__((ext_vector_type(8)));
typedef __bf16 bf16x4 __attribute__((ext_vector_type(4)));
typedef __bf16 bf16x2 __attribute__((ext_vector_type(2)));
typedef float  floatx4 __attribute__((ext_vector_type(4)));

// async 16B/lane global->LDS (LDS operand is wave-uniform base; HW adds lane*16)
#define GLD_LDS16(g, l) __builtin_amdgcn_global_load_lds(                      \
    (const __attribute__((address_space(1))) unsigned int*)(g),                \
    (__attribute__((address_space(3))) unsigned int*)(l), 16, 0, 0)

// ---------------------------------------------------------------------------
// Fused prep: blocks [0,9216) token-shift mix -> bf16 xk/xv/xr;
//             blocks [9216,11520) weight f32 -> bf16 pool (k|v|r|o rows).
// ---------------------------------------------------------------------------
__global__ __launch_bounds__(256)
void prep_kernel(const float* __restrict__ x,
                 const float* __restrict__ mk, const float* __restrict__ mv,
                 const float* __restrict__ mr,
                 const float* __restrict__ Wk, const float* __restrict__ Wv,
                 const float* __restrict__ Wr, const float* __restrict__ Wo,
                 __bf16* __restrict__ xk, __bf16* __restrict__ xv,
                 __bf16* __restrict__ xr, __bf16* __restrict__ wp)
{
    const int bid = blockIdx.x;
    if (bid < 9216) {
        const int i  = bid * 256 + threadIdx.x;       // one float4 of channels
        const int c4 = i % (Cq / 4);
        const int m  = i / (Cq / 4);
        const int t  = m % Tq;
        const int c0 = c4 * 4;

        const float4 xc = *(const float4*)(x + (size_t)m * Cq + c0);
        float4 xp = make_float4(0.f, 0.f, 0.f, 0.f);
        if (t > 0) xp = *(const float4*)(x + (size_t)(m - 1) * Cq + c0);

        const float4 k4 = *(const float4*)(mk + c0);
        const float4 v4 = *(const float4*)(mv + c0);
        const float4 r4 = *(const float4*)(mr + c0);

        bf16x4 ok = { (__bf16)fmaf(k4.x, xc.x - xp.x, xp.x),
                      (__bf16)fmaf(k4.y, xc.y - xp.y, xp.y),
                      (__bf16)fmaf(k4.z, xc.z - xp.z, xp.z),
                      (__bf16)fmaf(k4.w, xc.w - xp.w, xp.w) };
        bf16x4 ov = { (__bf16)fmaf(v4.x, xc.x - xp.x, xp.x),
                      (__bf16)fmaf(v4.y, xc.y - xp.y, xp.y),
                      (__bf16)fmaf(v4.z, xc.z - xp.z, xp.z),
                      (__bf16)fmaf(v4.w, xc.w - xp.w, xp.w) };
        bf16x4 orr = { (__bf16)fmaf(r4.x, xc.x - xp.x, xp.x),
                       (__bf16)fmaf(r4.y, xc.y - xp.y, xp.y),
                       (__bf16)fmaf(r4.z, xc.z - xp.z, xp.z),
                       (__bf16)fmaf(r4.w, xc.w - xp.w, xp.w) };
        const size_t o = (size_t)m * Cq + c0;
        *(bf16x4*)(xk + o) = ok;
        *(bf16x4*)(xv + o) = ov;
        *(bf16x4*)(xr + o) = orr;
    } else {
        const int i   = (bid - 9216) * 256 + threadIdx.x; // one float4
        const int a   = i / 147456;                       // which matrix
        const int off = (i - a * 147456) * 4;
        const float* s = (a == 0) ? Wk : (a == 1) ? Wv : (a == 2) ? Wr : Wo;
        const float4 v = *(const float4*)(s + off);
        bf16x4 r = { (__bf16)v.x, (__bf16)v.y, (__bf16)v.z, (__bf16)v.w };
        *(bf16x4*)(wp + (size_t)a * 589824 + off) = r;
    }
}

// ---------------------------------------------------------------------------
// bf16 MFMA GEMM, 128(tok) x 256(ch) tile, BK=64, 512 thr = 8 waves
// (wave wn=0..3 owns 64-ch quarter, wm=0..1 owns 64-token half; acc 4x4).
// 3-deep LDS pipeline with COUNTED vmcnt (T3+T4): while computing K-tile t
// from buf[t%3], stage K-tile t+2 into buf[(t+2)%3] (6 gld_lds per wave per
// K-tile).  End of each iteration: s_waitcnt vmcnt(6) (NEVER 0 in the loop:
// forces t+1's 6 loads landed, leaves t+2's 6 in flight across the barrier)
// + raw s_barrier.  Raw barriers throughout (no __syncthreads -> no implicit
// vmcnt(0) drain).  2 phases/iteration (kk=0,1), 16 MFMA each, setprio(1)
// around MFMA cluster (T5).  Staging & ds_read use the proven both-sides
// XOR-8 swizzle (0 bank conflicts measured on this pattern).
// Safety ledger:
//  - RAW (gld_lds -> ds_read): buf[t] staged at iter t-2; vmcnt(6) at end of
//    t-1 forces it landed; barrier publishes across waves.
//  - WAR (ds_read -> gld_lds overwrite): buf[t] re-written at iter t+1; all
//    iter-t reads complete before iter-t's final barrier (compiler lgkmcnt
//    before consuming MFMAs); writes issued after it.
//  - Last 2 iterations stage wrapped junk K-tiles into retired buffers
//    (uniform loop, constant vmcnt literal); never read.
// Grid: 1-D, XCD swizzle, strip-fastest (all-W 3.54 MB + X tiles < 4MB L2).
// ---------------------------------------------------------------------------
template<bool KVR>
__global__ __launch_bounds__(512, 2)
void mfma_gemm(const __bf16* __restrict__ A0, const __bf16* __restrict__ A1,
               const __bf16* __restrict__ A2,
               const __bf16* __restrict__ W,
               __bf16* __restrict__ OUTb, float* __restrict__ OUTf)
{
    __shared__ __bf16 LDS[3 * BUFE];   // 144 KiB

    const int STRIPS = KVR ? 9 : 3;

    // ---- XCD-aware swizzle (8 XCDs, 96 m-tiles = 8 x 12)
    const int i_    = blockIdx.x;
    const int xcd   = i_ & 7;
    const int j_    = i_ >> 3;
    const int strip = j_ % STRIPS;
    const int mt    = xcd * 12 + j_ / STRIPS;

    const int tid   = threadIdx.x;
    const int wv    = tid >> 6;           // 0..7
    const int lane  = tid & 63;
    const int m0    = mt * BM;
    const int matid = KVR ? strip / 3 : 0;
    const int n0    = (KVR ? strip % 3 : strip) * BN;

    const __bf16* X  = KVR ? (matid == 0 ? A0 : matid == 1 ? A1 : A2) : A0;
    const __bf16* Wb = W + (size_t)(matid * 768 + n0) * Kq;

    // ---- staging addresses: 1024 B per gld_lds = 8 rows of 128 B
    const int r8 = lane >> 3;             // row within 8-row group
    const int sc = (lane & 7) ^ r8;       // XOR-8 pre-swizzled source chunk
    const __bf16* gW[4];  int lW[4];      // W: 256 rows -> 4 instrs/wave
    const __bf16* gX[2];  int lX[2];      // X: 128 rows -> 2 instrs/wave
#pragma unroll
    for (int i = 0; i < 4; ++i) {
        const int row = (wv * 4 + i) * 8 + r8;
        gW[i] = Wb + (size_t)row * Kq + sc * 8;
        lW[i] = (wv * 4 + i) * 512;
    }
#pragma unroll
    for (int i = 0; i < 2; ++i) {
        const int row = (wv * 2 + i) * 8 + r8;
        gX[i] = X + (size_t)(m0 + row) * Kq + sc * 8;
        lX[i] = 16384 + (wv * 2 + i) * 512;
    }

    // ---- reader coords
    const int wn  = wv & 3;               // channel quarter (64)
    const int wm  = wv >> 2;              // token half (64)
    const int rW0 = wn * 64 + (lane & 15);
    const int rX0 = wm * 64 + (lane & 15);
    const int lk  = lane >> 4;            // 16B chunk within K=32

    floatx4 acc[4][4];
#pragma unroll
    for (int i = 0; i < 4; ++i)
#pragma unroll
        for (int j = 0; j < 4; ++j) acc[i][j] = (floatx4){0.f, 0.f, 0.f, 0.f};

    // ---- prologue: stage K-tiles 0,1 (12 loads/wave); wait oldest 6
#pragma unroll
    for (int b = 0; b < 2; ++b) {
        __bf16* Lb = LDS + b * BUFE;
#pragma unroll
        for (int i = 0; i < 4; ++i) GLD_LDS16(gW[i] + b * BK, Lb + lW[i]);
#pragma unroll
        for (int i = 0; i < 2; ++i) GLD_LDS16(gX[i] + b * BK, Lb + lX[i]);
    }
    asm volatile("s_waitcnt vmcnt(6)" ::: "memory");
    __builtin_amdgcn_s_barrier();

    for (int kt = 0; kt < KT; ++kt) {
        const __bf16* LW = LDS + (kt % 3) * BUFE;
        const __bf16* LX = LW + 16384;
        const int bs = (kt + 2) % 3;              // stage dest buffer
        const int ks = (kt + 2) % KT;             // stage src K-tile (wraps)
        __bf16* Lb = LDS + bs * BUFE;

        // ================= phase 0 (kk = 0) =================
        bf16x8 wF[4], xF[4];
#pragma unroll
        for (int i = 0; i < 4; ++i) {
            const int r = rW0 + i * 16;
            wF[i] = *(const bf16x8*)(LW + r * BK + (lk ^ (r & 7)) * 8);
        }
#pragma unroll
        for (int j = 0; j < 4; ++j) {
            const int r = rX0 + j * 16;
            xF[j] = *(const bf16x8*)(LX + r * BK + (lk ^ (r & 7)) * 8);
        }
        GLD_LDS16(gW[0] + ks * BK, Lb + lW[0]);
        GLD_LDS16(gW[1] + ks * BK, Lb + lW[1]);
        GLD_LDS16(gX[0] + ks * BK, Lb + lX[0]);
        __builtin_amdgcn_s_barrier();
        __builtin_amdgcn_s_setprio(1);
#pragma unroll
        for (int i = 0; i < 4; ++i)
#pragma unroll
            for (int j = 0; j < 4; ++j)
                acc[i][j] = __builtin_amdgcn_mfma_f32_16x16x32_bf16(
                    wF[i], xF[j], acc[i][j], 0, 0, 0);
        __builtin_amdgcn_s_setprio(0);
        __builtin_amdgcn_s_barrier();

        // ================= phase 1 (kk = 1) =================
#pragma unroll
        for (int i = 0; i < 4; ++i) {
            const int r = rW0 + i * 16;
            wF[i] = *(const bf16x8*)(LW + r * BK + ((4 | lk) ^ (r & 7)) * 8);
        }
#pragma unroll
        for (int j = 0; j < 4; ++j) {
            const int r = rX0 + j * 16;
            xF[j] = *(const bf16x8*)(LX + r * BK + ((4 | lk) ^ (r & 7)) * 8);
        }
        GLD_LDS16(gW[2] + ks * BK, Lb + lW[2]);
        GLD_LDS16(gW[3] + ks * BK, Lb + lW[3]);
        GLD_LDS16(gX[1] + ks * BK, Lb + lX[1]);
        asm volatile("s_waitcnt vmcnt(6)" ::: "memory");   // K-tile kt+1 landed
        __builtin_amdgcn_s_barrier();
        __builtin_amdgcn_s_setprio(1);
#pragma unroll
        for (int i = 0; i < 4; ++i)
#pragma unroll
            for (int j = 0; j < 4; ++j)
                acc[i][j] = __builtin_amdgcn_mfma_f32_16x16x32_bf16(
                    wF[i], xF[j], acc[i][j], 0, 0, 0);
        __builtin_amdgcn_s_setprio(0);
        __builtin_amdgcn_s_barrier();
    }

    // ---- epilogue: D col = token (lane&15), row-reg = 4 consecutive channels
#pragma unroll
    for (int j = 0; j < 4; ++j) {
        const int tok = m0 + wm * 64 + j * 16 + (lane & 15);
#pragma unroll
        for (int i = 0; i < 4; ++i) {
            const int ch = n0 + wn * 64 + i * 16 + (lane >> 4) * 4;
            if (KVR) {
                float v0 = acc[i][j][0], v1 = acc[i][j][1];
                float v2 = acc[i][j][2], v3 = acc[i][j][3];
                if (matid == 0) {
                    v0 = expf(fminf(v0, 60.f)); v1 = expf(fminf(v1, 60.f));
                    v2 = expf(fminf(v2, 60.f)); v3 = expf(fminf(v3, 60.f));
                } else if (matid == 2) {
                    v0 = 1.f / (1.f + expf(-v0)); v1 = 1.f / (1.f + expf(-v1));
                    v2 = 1.f / (1.f + expf(-v2)); v3 = 1.f / (1.f + expf(-v3));
                }
                bf16x4 o = { (__bf16)v0, (__bf16)v1, (__bf16)v2, (__bf16)v3 };
                *(bf16x4*)(OUTb + (size_t)matid * Mq * Nq +
                           (size_t)tok * Nq + ch) = o;
            } else {
                floatx4 o = acc[i][j];
                *(floatx4*)(OUTf + (size_t)tok * Nq + ch) = o;
            }
        }
    }
}

// ---------------------------------------------------------------------------
// Segmented RWKV scan (R1 version — best measured total): block = 64 lanes
// x 2 channels x 16 segments of 48.  Grid (6,16).
// ---------------------------------------------------------------------------
#define SEG 16
#define SLEN (Tq / SEG)   // 48

__global__ __launch_bounds__(1024)
void scan_kernel(const __bf16* __restrict__ kb, const __bf16* __restrict__ vb,
                 __bf16* rb,
                 const float* __restrict__ td, const float* __restrict__ tf)
{
    __shared__ float2 aS[SEG][64];
    __shared__ float2 bS[SEG][64];

    const int cx  = threadIdx.x;          // 0..63 -> channel pair
    const int seg = threadIdx.y;          // 0..15
    const int c0  = blockIdx.x * 128 + cx * 2;
    const int b   = blockIdx.y;

    const float d0 = expf(td[c0]),     d1 = expf(td[c0 + 1]);
    const float w0 = expf(-d0),        w1 = expf(-d1);      // per-step decay
    const float u0 = expf(tf[c0]),     u1 = expf(tf[c0 + 1]);

    const size_t base = ((size_t)b * Tq + seg * SLEN) * Cq + c0;

    // phase 1: local segment sums (zero init)
    float a0 = 0.f, a1 = 0.f, s0 = 0.f, s1 = 0.f;
#pragma unroll 4
    for (int t = 0; t < SLEN; ++t) {
        const size_t idx = base + (size_t)t * Cq;
        const bf16x2 k2 = *(const bf16x2*)(kb + idx);
        const bf16x2 v2 = *(const bf16x2*)(vb + idx);
        const float k0 = (float)k2[0], k1 = (float)k2[1];
        a0 = fmaf(w0, a0, k0 * (float)v2[0]);
        a1 = fmaf(w1, a1, k1 * (float)v2[1]);
        s0 = fmaf(w0, s0, k0);
        s1 = fmaf(w1, s1, k1);
    }
    aS[seg][cx] = make_float2(a0, a1);
    bS[seg][cx] = make_float2(s0, s1);
    __syncthreads();

    // phase 2: serial prefix over segments (first row of threads)
    if (seg == 0) {
        const float W0 = expf(-d0 * (float)SLEN);   // w0^SLEN
        const float W1 = expf(-d1 * (float)SLEN);
        float ia0 = 0.f, ia1 = 0.f, ib0 = 0.f, ib1 = 0.f;
#pragma unroll
        for (int s = 0; s < SEG; ++s) {
            const float2 ta = aS[s][cx];
            const float2 tb = bS[s][cx];
            aS[s][cx] = make_float2(ia0, ia1);
            bS[s][cx] = make_float2(ib0, ib1);
            ia0 = fmaf(W0, ia0, ta.x);  ia1 = fmaf(W1, ia1, ta.y);
            ib0 = fmaf(W0, ib0, tb.x);  ib1 = fmaf(W1, ib1, tb.y);
        }
    }
    __syncthreads();

    // phase 3: outputs with incoming state
    const float2 ain = aS[seg][cx];
    const float2 bin = bS[seg][cx];
    a0 = ain.x; a1 = ain.y; s0 = bin.x; s1 = bin.y;
#pragma unroll 2
    for (int t = 0; t < SLEN; ++t) {
        const size_t idx = base + (size_t)t * Cq;
        const bf16x2 k2 = *(const bf16x2*)(kb + idx);
        const bf16x2 v2 = *(const bf16x2*)(vb + idx);
        const bf16x2 r2 = *(const bf16x2*)(rb + idx);   // sigmoid(r)
        const float k0 = (float)k2[0], k1 = (float)k2[1];
        const float kv0 = k0 * (float)v2[0], kv1 = k1 * (float)v2[1];
        const float n0 = fmaf(u0, kv0, a0), n1 = fmaf(u1, kv1, a1);
        const float e0 = fmaf(u0, k0, s0) + 1e-8f;
        const float e1 = fmaf(u1, k1, s1) + 1e-8f;
        bf16x2 o = { (__bf16)((float)r2[0] * n0 / e0),
                     (__bf16)((float)r2[1] * n1 / e1) };
        *(bf16x2*)(rb + idx) = o;
        a0 = fmaf(w0, a0, kv0);  a1 = fmaf(w1, a1, kv1);
        s0 = fmaf(w0, s0, k0);   s1 = fmaf(w1, s1, k1);
    }
}

extern "C" void kernel_launch(void* const* d_in, const int* in_sizes, int n_in,
                              void* d_out, int out_size, void* d_ws, size_t ws_size,
                              hipStream_t stream)
{
    const float* x  = (const float*)d_in[0];
    const float* td = (const float*)d_in[1];
    const float* tf = (const float*)d_in[2];
    const float* mk = (const float*)d_in[3];
    const float* mv = (const float*)d_in[4];
    const float* mr = (const float*)d_in[5];
    const float* Wk = (const float*)d_in[6];
    const float* Wv = (const float*)d_in[7];
    const float* Wr = (const float*)d_in[8];
    const float* Wo = (const float*)d_in[9];

    const size_t MC = (size_t)Mq * Cq;      // 9,437,184 elems

    // d_out doubles as scratch for xk/xv (2 x bf16 MC = out bytes exactly)
    __bf16* xk = (__bf16*)d_out;
    __bf16* xv = xk + MC;

    // ws: xr | kbuf | vbuf | rbuf(->rwkv) | weights(bf16 x4)  = ~80 MB
    __bf16* xr   = (__bf16*)d_ws;
    __bf16* kbuf = xr + MC;                 // kbuf,vbuf,rbuf contiguous
    __bf16* vbuf = kbuf + MC;
    __bf16* rbuf = vbuf + MC;
    __bf16* Wp   = rbuf + MC;
    __bf16* Wob  = Wp + 3 * 589824;

    prep_kernel<<<11520, 256, 0, stream>>>(x, mk, mv, mr, Wk, Wv, Wr, Wo,
                                           xk, xv, xr, Wp);

    // fused k|v|r GEMM: 9 strips x 96 m-tiles, XCD-swizzled 1-D grid
    mfma_gemm<true><<<9 * 96, 512, 0, stream>>>(
        xk, xv, xr, Wp, kbuf, nullptr);

    scan_kernel<<<dim3(Cq / 128, Bq), dim3(64, SEG), 0, stream>>>(
        kbuf, vbuf, rbuf, td, tf);

    mfma_gemm<false><<<3 * 96, 512, 0, stream>>>(
        rbuf, nullptr, nullptr, Wob, nullptr, (float*)d_out);
}

// Round 5
// 217.665 us; speedup vs baseline: 1.1183x; 1.1183x over previous
//
#include <hip/hip_runtime.h>
#include <math.h>

#define Mq 12288          // B*T
#define Nq 768            // C (per-matrix output width)
#define Kq 768            // C (reduce dim)
#define Tq 768
#define Bq 16
#define Cq 768
#define BK 64             // K-tile (bf16) = 128 B = 8 x 16B chunks
#define BM 128            // M-tile (tokens) — proven 128x128 tile (R1: 657 TF)

typedef __bf16 bf16x8 __attribute__((ext_vector_type(8)));
typedef __bf16 bf16x4 __attribute__((ext_vector_type(4)));
typedef __bf16 bf16x2 __attribute__((ext_vector_type(2)));
typedef float  floatx4 __attribute__((ext_vector_type(4)));

// async 16B/lane global->LDS (LDS operand is wave-uniform base; HW adds lane*16)
#define GLD_LDS16(g, l) __builtin_amdgcn_global_load_lds(                      \
    (const __attribute__((address_space(1))) unsigned int*)(g),                \
    (__attribute__((address_space(3))) unsigned int*)(l), 16, 0, 0)

// ---------------------------------------------------------------------------
// Fused prep: blocks [0,9216) token-shift mix -> bf16 xk/xv/xr;
//             blocks [9216,11520) weight f32 -> bf16 pool (k|v|r|o rows).
// ---------------------------------------------------------------------------
__global__ __launch_bounds__(256)
void prep_kernel(const float* __restrict__ x,
                 const float* __restrict__ mk, const float* __restrict__ mv,
                 const float* __restrict__ mr,
                 const float* __restrict__ Wk, const float* __restrict__ Wv,
                 const float* __restrict__ Wr, const float* __restrict__ Wo,
                 __bf16* __restrict__ xk, __bf16* __restrict__ xv,
                 __bf16* __restrict__ xr, __bf16* __restrict__ wp)
{
    const int bid = blockIdx.x;
    if (bid < 9216) {
        const int i  = bid * 256 + threadIdx.x;       // one float4 of channels
        const int c4 = i % (Cq / 4);
        const int m  = i / (Cq / 4);
        const int t  = m % Tq;
        const int c0 = c4 * 4;

        const float4 xc = *(const float4*)(x + (size_t)m * Cq + c0);
        float4 xp = make_float4(0.f, 0.f, 0.f, 0.f);
        if (t > 0) xp = *(const float4*)(x + (size_t)(m - 1) * Cq + c0);

        const float4 k4 = *(const float4*)(mk + c0);
        const float4 v4 = *(const float4*)(mv + c0);
        const float4 r4 = *(const float4*)(mr + c0);

        bf16x4 ok = { (__bf16)fmaf(k4.x, xc.x - xp.x, xp.x),
                      (__bf16)fmaf(k4.y, xc.y - xp.y, xp.y),
                      (__bf16)fmaf(k4.z, xc.z - xp.z, xp.z),
                      (__bf16)fmaf(k4.w, xc.w - xp.w, xp.w) };
        bf16x4 ov = { (__bf16)fmaf(v4.x, xc.x - xp.x, xp.x),
                      (__bf16)fmaf(v4.y, xc.y - xp.y, xp.y),
                      (__bf16)fmaf(v4.z, xc.z - xp.z, xp.z),
                      (__bf16)fmaf(v4.w, xc.w - xp.w, xp.w) };
        bf16x4 orr = { (__bf16)fmaf(r4.x, xc.x - xp.x, xp.x),
                       (__bf16)fmaf(r4.y, xc.y - xp.y, xp.y),
                       (__bf16)fmaf(r4.z, xc.z - xp.z, xp.z),
                       (__bf16)fmaf(r4.w, xc.w - xp.w, xp.w) };
        const size_t o = (size_t)m * Cq + c0;
        *(bf16x4*)(xk + o) = ok;
        *(bf16x4*)(xv + o) = ov;
        *(bf16x4*)(xr + o) = orr;
    } else {
        const int i   = (bid - 9216) * 256 + threadIdx.x; // one float4
        const int a   = i / 147456;                       // which matrix
        const int off = (i - a * 147456) * 4;
        const float* s = (a == 0) ? Wk : (a == 1) ? Wv : (a == 2) ? Wr : Wo;
        const float4 v = *(const float4*)(s + off);
        bf16x4 r = { (__bf16)v.x, (__bf16)v.y, (__bf16)v.z, (__bf16)v.w };
        *(bf16x4*)(wp + (size_t)a * 589824 + off) = r;
    }
}

// ---------------------------------------------------------------------------
// bf16 MFMA GEMM, 128x128 tile, BK=64, 256 thr (4 waves, each a 64x64
// quadrant), operand-swapped (W = MFMA A).  m97-structure: single-buffered
// LDS, 2 barriers per K-step, global_load_lds width=16, XOR-8 swizzle
// applied on BOTH sides (pre-swizzled global source + swizzled ds_read).
// R1-verified: 66.2 us, 657 TF, 0 bank conflicts, FETCH ~74 MB (near-ideal).
// 32 KB LDS -> ~3 blocks/CU: inter-block wave overlap hides the per-K-step
// vmcnt drain (m114 mechanism); deeper explicit pipelines measured WORSE
// on this shape (R4: 79 us at 1 block/CU).  Lane closed.
// 1-D grid with XCD-aware swizzle: xcd = blockIdx&7 owns m-tiles
// [xcd*12, xcd*12+12), strip-fastest within -> per-XCD L2 working set =
// all B strips (KVR: 3.5 MB) + current A tiles (~0.6 MB), < 4 MB L2.
// STRIPS = 18 (KVR: k|v|r x 6 n-tiles) or 6 (final Wo GEMM).
// ---------------------------------------------------------------------------
template<bool KVR>
__global__ __launch_bounds__(256, 3)
void mfma_gemm(const __bf16* __restrict__ A0, const __bf16* __restrict__ A1,
               const __bf16* __restrict__ A2,
               const __bf16* __restrict__ W,
               __bf16* __restrict__ OUTb, float* __restrict__ OUTf)
{
    __shared__ __bf16 As[BM * BK];    // 16 KB (tokens)
    __shared__ __bf16 Bs[128 * BK];   // 16 KB (channels)

    const int STRIPS = KVR ? 18 : 6;

    // ---- XCD-aware block swizzle (8 XCDs, 96 m-tiles = 8 x 12)
    const int i_    = blockIdx.x;
    const int xcd   = i_ & 7;
    const int j_    = i_ >> 3;
    const int strip = j_ % STRIPS;
    const int mt    = xcd * 12 + j_ / STRIPS;

    const int tid   = threadIdx.x;
    const int wave  = tid >> 6;
    const int lane  = tid & 63;
    const int m0    = mt * BM;
    const int matid = KVR ? strip / 6 : 0;
    const int n0    = KVR ? (strip % 6) * 128 : strip * 128;
    const int wn0   = strip * 128;

    const __bf16* A = KVR ? (matid == 0 ? A0 : matid == 1 ? A1 : A2) : A0;

    // ---- staging: 1024 B per global_load_lds instr = 8 rows of 128 B
    const int r8 = lane >> 3;             // row within 8-row group
    const int sc = (lane & 7) ^ r8;       // XOR-8 swizzled source chunk
    const __bf16* gA[4];  __bf16* lA[4];
    const __bf16* gB[4];  __bf16* lB[4];
#pragma unroll
    for (int i = 0; i < 4; ++i) {
        const int row = (wave * 4 + i) * 8 + r8;
        gA[i] = A + (size_t)(m0 + row) * Kq + sc * 8;
        lA[i] = As + (wave * 4 + i) * 512;
        gB[i] = W + (size_t)(wn0 + row) * Kq + sc * 8;
        lB[i] = Bs + (wave * 4 + i) * 512;
    }

    // ---- reader coords: wave (wm,wn) owns tokens [wm*64,+64) x ch [wn*64,+64)
    const int wm   = wave & 1;
    const int wn   = wave >> 1;
    const int xRow = wm * 64 + (lane & 15);   // + j*16, in As
    const int wRow = wn * 64 + (lane & 15);   // + i*16, in Bs
    const int lk   = lane >> 4;               // logical 16B chunk within K=32

    floatx4 acc[4][4];
#pragma unroll
    for (int i = 0; i < 4; ++i)
#pragma unroll
        for (int j = 0; j < 4; ++j) acc[i][j] = (floatx4){0.f, 0.f, 0.f, 0.f};

    for (int kt = 0; kt < Kq / BK; ++kt) {
#pragma unroll
        for (int i = 0; i < 4; ++i) { GLD_LDS16(gA[i], lA[i]); gA[i] += BK; }
#pragma unroll
        for (int i = 0; i < 4; ++i) { GLD_LDS16(gB[i], lB[i]); gB[i] += BK; }
        __syncthreads();                  // drains vmcnt(0): tile in LDS

#pragma unroll
        for (int kk = 0; kk < 2; ++kk) {
            bf16x8 wF[4], xF[4];
#pragma unroll
            for (int i = 0; i < 4; ++i) {
                const int r = wRow + i * 16;
                wF[i] = *(const bf16x8*)(Bs + r * BK +
                                         (((kk << 2) | lk) ^ (r & 7)) * 8);
            }
#pragma unroll
            for (int j = 0; j < 4; ++j) {
                const int r = xRow + j * 16;
                xF[j] = *(const bf16x8*)(As + r * BK +
                                         (((kk << 2) | lk) ^ (r & 7)) * 8);
            }
#pragma unroll
            for (int i = 0; i < 4; ++i)
#pragma unroll
                for (int j = 0; j < 4; ++j)
                    acc[i][j] = __builtin_amdgcn_mfma_f32_16x16x32_bf16(
                        wF[i], xF[j], acc[i][j], 0, 0, 0);
        }
        __syncthreads();                  // LDS reads done before overwrite
    }

    // ---- epilogue: D col = token (lane&15), row-reg = 4 consecutive channels
#pragma unroll
    for (int j = 0; j < 4; ++j) {
        const int tok = m0 + wm * 64 + j * 16 + (lane & 15);
#pragma unroll
        for (int i = 0; i < 4; ++i) {
            const int ch = n0 + wn * 64 + i * 16 + (lane >> 4) * 4;
            if (KVR) {
                float v0 = acc[i][j][0], v1 = acc[i][j][1];
                float v2 = acc[i][j][2], v3 = acc[i][j][3];
                if (matid == 0) {
                    v0 = expf(fminf(v0, 60.f)); v1 = expf(fminf(v1, 60.f));
                    v2 = expf(fminf(v2, 60.f)); v3 = expf(fminf(v3, 60.f));
                } else if (matid == 2) {
                    v0 = 1.f / (1.f + expf(-v0)); v1 = 1.f / (1.f + expf(-v1));
                    v2 = 1.f / (1.f + expf(-v2)); v3 = 1.f / (1.f + expf(-v3));
                }
                bf16x4 o = { (__bf16)v0, (__bf16)v1, (__bf16)v2, (__bf16)v3 };
                *(bf16x4*)(OUTb + (size_t)matid * Mq * Nq +
                           (size_t)tok * Nq + ch) = o;
            } else {
                floatx4 o = acc[i][j];
                *(floatx4*)(OUTf + (size_t)tok * Nq + ch) = o;
            }
        }
    }
}

// ---------------------------------------------------------------------------
// Segmented RWKV scan (R1 structure): block = 64 lanes x 2 channels x 16
// segments of 48.  Grid (6,16).  Change vs R1: the two per-element precise
// f32 divisions in phase 3 -> v_rcp_f32 + mul (saves ~10 VALU instrs per
// division x 9.4M divisions; ~1 ulp error, negligible vs bf16 rounding).
// ---------------------------------------------------------------------------
#define SEG 16
#define SLEN (Tq / SEG)   // 48

__global__ __launch_bounds__(1024)
void scan_kernel(const __bf16* __restrict__ kb, const __bf16* __restrict__ vb,
                 __bf16* rb,
                 const float* __restrict__ td, const float* __restrict__ tf)
{
    __shared__ float2 aS[SEG][64];
    __shared__ float2 bS[SEG][64];

    const int cx  = threadIdx.x;          // 0..63 -> channel pair
    const int seg = threadIdx.y;          // 0..15
    const int c0  = blockIdx.x * 128 + cx * 2;
    const int b   = blockIdx.y;

    const float d0 = expf(td[c0]),     d1 = expf(td[c0 + 1]);
    const float w0 = expf(-d0),        w1 = expf(-d1);      // per-step decay
    const float u0 = expf(tf[c0]),     u1 = expf(tf[c0 + 1]);

    const size_t base = ((size_t)b * Tq + seg * SLEN) * Cq + c0;

    // phase 1: local segment sums (zero init)
    float a0 = 0.f, a1 = 0.f, s0 = 0.f, s1 = 0.f;
#pragma unroll 4
    for (int t = 0; t < SLEN; ++t) {
        const size_t idx = base + (size_t)t * Cq;
        const bf16x2 k2 = *(const bf16x2*)(kb + idx);
        const bf16x2 v2 = *(const bf16x2*)(vb + idx);
        const float k0 = (float)k2[0], k1 = (float)k2[1];
        a0 = fmaf(w0, a0, k0 * (float)v2[0]);
        a1 = fmaf(w1, a1, k1 * (float)v2[1]);
        s0 = fmaf(w0, s0, k0);
        s1 = fmaf(w1, s1, k1);
    }
    aS[seg][cx] = make_float2(a0, a1);
    bS[seg][cx] = make_float2(s0, s1);
    __syncthreads();

    // phase 2: serial prefix over segments (first row of threads)
    if (seg == 0) {
        const float W0 = expf(-d0 * (float)SLEN);   // w0^SLEN
        const float W1 = expf(-d1 * (float)SLEN);
        float ia0 = 0.f, ia1 = 0.f, ib0 = 0.f, ib1 = 0.f;
#pragma unroll
        for (int s = 0; s < SEG; ++s) {
            const float2 ta = aS[s][cx];
            const float2 tb = bS[s][cx];
            aS[s][cx] = make_float2(ia0, ia1);
            bS[s][cx] = make_float2(ib0, ib1);
            ia0 = fmaf(W0, ia0, ta.x);  ia1 = fmaf(W1, ia1, ta.y);
            ib0 = fmaf(W0, ib0, tb.x);  ib1 = fmaf(W1, ib1, tb.y);
        }
    }
    __syncthreads();

    // phase 3: outputs with incoming state
    const float2 ain = aS[seg][cx];
    const float2 bin = bS[seg][cx];
    a0 = ain.x; a1 = ain.y; s0 = bin.x; s1 = bin.y;
#pragma unroll 2
    for (int t = 0; t < SLEN; ++t) {
        const size_t idx = base + (size_t)t * Cq;
        const bf16x2 k2 = *(const bf16x2*)(kb + idx);
        const bf16x2 v2 = *(const bf16x2*)(vb + idx);
        const bf16x2 r2 = *(const bf16x2*)(rb + idx);   // sigmoid(r)
        const float k0 = (float)k2[0], k1 = (float)k2[1];
        const float kv0 = k0 * (float)v2[0], kv1 = k1 * (float)v2[1];
        const float n0 = fmaf(u0, kv0, a0), n1 = fmaf(u1, kv1, a1);
        const float e0 = fmaf(u0, k0, s0) + 1e-8f;
        const float e1 = fmaf(u1, k1, s1) + 1e-8f;
        const float i0 = __builtin_amdgcn_rcpf(e0);
        const float i1 = __builtin_amdgcn_rcpf(e1);
        bf16x2 o = { (__bf16)((float)r2[0] * n0 * i0),
                     (__bf16)((float)r2[1] * n1 * i1) };
        *(bf16x2*)(rb + idx) = o;
        a0 = fmaf(w0, a0, kv0);  a1 = fmaf(w1, a1, kv1);
        s0 = fmaf(w0, s0, k0);   s1 = fmaf(w1, s1, k1);
    }
}

extern "C" void kernel_launch(void* const* d_in, const int* in_sizes, int n_in,
                              void* d_out, int out_size, void* d_ws, size_t ws_size,
                              hipStream_t stream)
{
    const float* x  = (const float*)d_in[0];
    const float* td = (const float*)d_in[1];
    const float* tf = (const float*)d_in[2];
    const float* mk = (const float*)d_in[3];
    const float* mv = (const float*)d_in[4];
    const float* mr = (const float*)d_in[5];
    const float* Wk = (const float*)d_in[6];
    const float* Wv = (const float*)d_in[7];
    const float* Wr = (const float*)d_in[8];
    const float* Wo = (const float*)d_in[9];

    const size_t MC = (size_t)Mq * Cq;      // 9,437,184 elems

    // d_out doubles as scratch for xk/xv (2 x bf16 MC = out bytes exactly)
    __bf16* xk = (__bf16*)d_out;
    __bf16* xv = xk + MC;

    // ws: xr | kbuf | vbuf | rbuf(->rwkv) | weights(bf16 x4)  = ~80 MB
    __bf16* xr   = (__bf16*)d_ws;
    __bf16* kbuf = xr + MC;                 // kbuf,vbuf,rbuf contiguous
    __bf16* vbuf = kbuf + MC;
    __bf16* rbuf = vbuf + MC;
    __bf16* Wp   = rbuf + MC;
    __bf16* Wob  = Wp + 3 * 589824;

    prep_kernel<<<11520, 256, 0, stream>>>(x, mk, mv, mr, Wk, Wv, Wr, Wo,
                                           xk, xv, xr, Wp);

    // fused k|v|r GEMM: 18 strips x 96 m-tiles, XCD-swizzled 1-D grid
    mfma_gemm<true><<<18 * 96, 256, 0, stream>>>(
        xk, xv, xr, Wp, kbuf, nullptr);

    scan_kernel<<<dim3(Cq / 128, Bq), dim3(64, SEG), 0, stream>>>(
        kbuf, vbuf, rbuf, td, tf);

    mfma_gemm<false><<<6 * 96, 256, 0, stream>>>(
        rbuf, nullptr, nullptr, Wob, nullptr, (float*)d_out);
}